// Round 1
// baseline (178.487 us; speedup 1.0000x reference)
//
#include <hip/hip_runtime.h>
#include <math.h>

// CRNN fused kernel, f32 VALU version (round 0: correctness + decent perf).
// Dims fixed by the problem:
#define NSPEC 32      // NS
#define NIN   34      // NS + 2
#define NREAC 256     // NR
#define NGRID 2048    // NG
#define WROW  68      // LDS row: 34 w_in + 1 w_b + 1 pad + 32 w_out  (68*4 bytes, 16B-aligned rows)
#define HALF_R 128    // reactions staged per LDS pass (2 passes keep static LDS < 64KB)

__device__ __forceinline__ float clampf(float x, float lo, float hi) {
    return fminf(fmaxf(x, lo), hi);
}

#define FMA4(acc, a, b)                         \
    acc.x = fmaf(a.x, b.x, acc.x);              \
    acc.y = fmaf(a.y, b.y, acc.y);              \
    acc.z = fmaf(a.z, b.z, acc.z);              \
    acc.w = fmaf(a.w, b.w, acc.w);

#define FMAS4(acc, s, b)                        \
    acc.x = fmaf(s, b.x, acc.x);                \
    acc.y = fmaf(s, b.y, acc.y);                \
    acc.z = fmaf(s, b.z, acc.z);                \
    acc.w = fmaf(s, b.w, acc.w);

__device__ __forceinline__ void stage_weights(int tid, int half, float* s_w,
                                              const float* __restrict__ w_in,
                                              const float* __restrict__ w_b,
                                              const float* __restrict__ w_out) {
    // 256 threads stage 128 reaction-rows of 68 floats.
    // threads [0,128): w_in column + w_b + pad; threads [128,256): w_out column.
    const int r  = tid & (HALF_R - 1);
    const int rg = half * HALF_R + r;            // global reaction index
    float* dst = s_w + r * WROW;
    if (tid < HALF_R) {
        #pragma unroll
        for (int k = 0; k < NIN; ++k) dst[k] = w_in[k * NREAC + rg];  // coalesced across lanes
        dst[NIN]     = w_b[rg];
        dst[NIN + 1] = 0.0f;                      // pad (paired with wv[35] = 0)
    } else {
        #pragma unroll
        for (int s = 0; s < NSPEC; ++s) dst[36 + s] = w_out[s * NREAC + rg];
    }
}

__global__ __launch_bounds__(256) void crnn_fused(
    const float* __restrict__ u,       // [B, 32]
    const float* __restrict__ t,       // [B]
    const float* __restrict__ g_ts,    // [2048] sorted time grid
    const float* __restrict__ T_tab,   // [2048]
    const float* __restrict__ w_in,    // [34, 256]
    const float* __restrict__ w_b,     // [256]
    const float* __restrict__ w_out,   // [32, 256]
    float* __restrict__ out)           // [B, 32]
{
    __shared__ float s_ts[NGRID];
    __shared__ float s_w[HALF_R * WROW];

    const int tid = threadIdx.x;

    // ---- stage time grid + first weight half ----
    #pragma unroll
    for (int i = 0; i < NGRID / 256; ++i)
        s_ts[i * 256 + tid] = g_ts[i * 256 + tid];
    stage_weights(tid, 0, s_w, w_in, w_b, w_out);
    __syncthreads();

    const long long s0 = (long long)blockIdx.x * 512 + tid;   // sample 0
    const long long s1 = s0 + 256;                             // sample 1

    // ---- prologue: w_v for both samples ----
    // wv[j].{x..w} = log(clip(u)) for species 4j..4j+3 (j<8);
    // wv[8] = { -1/(R*T), log(T), 1.0 (bias), 0.0 (pad) }
    float4 wv0[9], wv1[9];
    {
        const float4* u0 = reinterpret_cast<const float4*>(u + s0 * NSPEC);
        const float4* u1 = reinterpret_cast<const float4*>(u + s1 * NSPEC);
        #pragma unroll
        for (int j = 0; j < 8; ++j) {
            float4 a = u0[j];
            float4 b = u1[j];
            wv0[j].x = logf(clampf(a.x, 1e-5f, 60.0f));
            wv0[j].y = logf(clampf(a.y, 1e-5f, 60.0f));
            wv0[j].z = logf(clampf(a.z, 1e-5f, 60.0f));
            wv0[j].w = logf(clampf(a.w, 1e-5f, 60.0f));
            wv1[j].x = logf(clampf(b.x, 1e-5f, 60.0f));
            wv1[j].y = logf(clampf(b.y, 1e-5f, 60.0f));
            wv1[j].z = logf(clampf(b.z, 1e-5f, 60.0f));
            wv1[j].w = logf(clampf(b.w, 1e-5f, 60.0f));
        }
        // jnp.interp clone: searchsorted(side='right') via upper_bound with
        // IDENTICAL comparisons on the staged f32 grid, then
        // f = fp[i-1] + ((x - xp[i-1]) / (xp[i]-xp[i-1])) * (fp[i]-fp[i-1])
        float tt[2] = { t[s0], t[s1] };
        float Tv[2];
        #pragma unroll
        for (int q = 0; q < 2; ++q) {
            float x = tt[q];
            int lo = 0, hi = NGRID;
            while (lo < hi) {
                int mid = (lo + hi) >> 1;
                if (x < s_ts[mid]) hi = mid; else lo = mid + 1;
            }
            int i = lo;
            i = (i < 1) ? 1 : ((i > NGRID - 1) ? NGRID - 1 : i);
            float xp0 = s_ts[i - 1], xp1 = s_ts[i];
            float fp0 = T_tab[i - 1], fp1 = T_tab[i];
            Tv[q] = fp0 + ((x - xp0) / (xp1 - xp0)) * (fp1 - fp0);
        }
        wv0[8].x = -1.0f / (0.0019872036f * Tv[0]);
        wv0[8].y = logf(Tv[0]);
        wv0[8].z = 1.0f;
        wv0[8].w = 0.0f;
        wv1[8].x = -1.0f / (0.0019872036f * Tv[1]);
        wv1[8].y = logf(Tv[1]);
        wv1[8].z = 1.0f;
        wv1[8].w = 0.0f;
    }

    float4 du0[8], du1[8];
    #pragma unroll
    for (int j = 0; j < 8; ++j) {
        du0[j] = make_float4(0.f, 0.f, 0.f, 0.f);
        du1[j] = make_float4(0.f, 0.f, 0.f, 0.f);
    }

    // ---- main loop over reactions, two LDS halves ----
    for (int half = 0; half < 2; ++half) {
        if (half) {
            __syncthreads();                              // all waves done reading half 0
            stage_weights(tid, 1, s_w, w_in, w_b, w_out);
            __syncthreads();
        }
        for (int r = 0; r < HALF_R; ++r) {
            const float4* row4 = reinterpret_cast<const float4*>(&s_w[r * WROW]);
            float4 a0 = make_float4(0.f, 0.f, 0.f, 0.f);
            float4 a1 = make_float4(0.f, 0.f, 0.f, 0.f);
            #pragma unroll
            for (int j = 0; j < 9; ++j) {
                float4 w4 = row4[j];                       // wave-uniform LDS broadcast
                FMA4(a0, wv0[j], w4);
                FMA4(a1, wv1[j], w4);
            }
            float i0 = (a0.x + a0.y) + (a0.z + a0.w);
            float i1 = (a1.x + a1.y) + (a1.z + a1.w);
            float e0 = expf(clampf(i0, -30.0f, 30.0f));
            float e1 = expf(clampf(i1, -30.0f, 30.0f));
            #pragma unroll
            for (int j = 0; j < 8; ++j) {
                float4 w4 = row4[9 + j];
                FMAS4(du0[j], e0, w4);
                FMAS4(du1[j], e1, w4);
            }
        }
    }

    // ---- epilogue: clip and store ----
    float4* o0 = reinterpret_cast<float4*>(out + s0 * NSPEC);
    float4* o1 = reinterpret_cast<float4*>(out + s1 * NSPEC);
    #pragma unroll
    for (int j = 0; j < 8; ++j) {
        float4 v = du0[j];
        v.x = clampf(v.x, -1e4f, 1e4f);
        v.y = clampf(v.y, -1e4f, 1e4f);
        v.z = clampf(v.z, -1e4f, 1e4f);
        v.w = clampf(v.w, -1e4f, 1e4f);
        o0[j] = v;
        float4 w = du1[j];
        w.x = clampf(w.x, -1e4f, 1e4f);
        w.y = clampf(w.y, -1e4f, 1e4f);
        w.z = clampf(w.z, -1e4f, 1e4f);
        w.w = clampf(w.w, -1e4f, 1e4f);
        o1[j] = w;
    }
}

extern "C" void kernel_launch(void* const* d_in, const int* in_sizes, int n_in,
                              void* d_out, int out_size, void* d_ws, size_t ws_size,
                              hipStream_t stream) {
    const float* u      = (const float*)d_in[0];
    const float* t      = (const float*)d_in[1];
    const float* tsteps = (const float*)d_in[2];
    const float* T_tab  = (const float*)d_in[3];
    // d_in[4] = P_tab : computed-but-unused in the reference
    const float* w_in   = (const float*)d_in[5];
    const float* w_b    = (const float*)d_in[6];
    const float* w_out  = (const float*)d_in[7];
    float* out = (float*)d_out;

    const int B = in_sizes[0] / NSPEC;      // 262144
    const int grid = B / 512;               // 512 samples per block (2 per thread)
    crnn_fused<<<grid, 256, 0, stream>>>(u, t, tsteps, T_tab, w_in, w_b, w_out, out);
}

// Round 2
// 103.241 us; speedup vs baseline: 1.7288x; 1.7288x over previous
//
#include <hip/hip_runtime.h>

// CRNN fused kernel, round 1: bf16 MFMA with hi/lo 3-term splits.
// GEMM1 swapped (D1 = [reaction x sample]) so its accumulator quads feed
// 16x16x16 MFMAs for GEMM2 directly (no cross-lane transpose).
#define NSPEC 32
#define NREAC 256
#define NGRID 2048

typedef __bf16 bf16x8_t __attribute__((ext_vector_type(8)));
typedef short shortx4_t __attribute__((ext_vector_type(4)));
typedef float f32x4_t  __attribute__((ext_vector_type(4)));

union F8 { ushort u[8]; bf16x8_t v; };
union F4 { ushort u[4]; shortx4_t v; };

__device__ __forceinline__ ushort f2bh(float x) {          // f32 -> bf16 bits (RNE)
    uint b = __float_as_uint(x);
    return (ushort)((b + 0x7FFFu + ((b >> 16) & 1u)) >> 16);
}
__device__ __forceinline__ float bh2f(ushort h) {           // bf16 bits -> f32 (exact)
    return __uint_as_float(((uint)h) << 16);
}
__device__ __forceinline__ float clampf(float x, float lo, float hi) {
    return fminf(fmaxf(x, lo), hi);
}

__global__ __launch_bounds__(256, 2) void crnn_mfma(
    const float* __restrict__ u,       // [B,32]
    const float* __restrict__ t,       // [B]
    const float* __restrict__ tsteps,  // [2048] uniform-ish sorted grid
    const float* __restrict__ T_tab,   // [2048]
    const float* __restrict__ w_in,    // [34,256]
    const float* __restrict__ w_b,     // [256]
    const float* __restrict__ w_out,   // [32,256]
    float* __restrict__ out,           // [B,32]
    int iters)
{
    // W1 row r: [Wh(k0..7) | Wl(k0..7) | Wh(k8..15) | Wl(k8..15) | ... | mix(8)]
    //   mix = {Wh32,Wh33,Wh32,Wh33,Wl32,Wl33,wb_h,wb_l}; stride 72us=144B (16B-mult)
    __shared__ ushort sW1[256][72];    // 36 KB
    // W2 row s: per k-quad q: [W2h(q) 4us | W2l(q) 4us]; stride 520us=1040B
    __shared__ ushort sW2[32][520];    // 32.5 KB

    const int tid = threadIdx.x;

    // ---- stage weights (hi/lo bf16 split), once per block ----
    {
        const int r = tid;                       // 256 threads = 256 reactions
        #pragma unroll
        for (int k = 0; k < 32; ++k) {
            float f = w_in[k * NREAC + r];       // coalesced across threads
            ushort h = f2bh(f), l = f2bh(f - bh2f(h));
            sW1[r][(k >> 3) * 16 + (k & 7)]     = h;
            sW1[r][(k >> 3) * 16 + (k & 7) + 8] = l;
        }
        float f32v = w_in[32 * NREAC + r];       // -1/(R*T) weight row
        float f33v = w_in[33 * NREAC + r];       // log T weight row
        float fbv  = w_b[r];
        ushort h32 = f2bh(f32v), l32 = f2bh(f32v - bh2f(h32));
        ushort h33 = f2bh(f33v), l33 = f2bh(f33v - bh2f(h33));
        ushort hb  = f2bh(fbv),  lb  = f2bh(fbv  - bh2f(hb));
        sW1[r][64] = h32; sW1[r][65] = h33; sW1[r][66] = h32; sW1[r][67] = h33;
        sW1[r][68] = l32; sW1[r][69] = l33; sW1[r][70] = hb;  sW1[r][71] = lb;
    }
    {
        const int s2 = tid >> 3;                 // spec 0..31
        const int kb = (tid & 7) * 32;           // 32 reactions per thread
        for (int k = kb; k < kb + 32; ++k) {
            float f = w_out[s2 * NREAC + k];
            ushort h = f2bh(f), l = f2bh(f - bh2f(h));
            sW2[s2][(k >> 2) * 8 + (k & 3)]     = h;
            sW2[s2][(k >> 2) * 8 + (k & 3) + 4] = l;
        }
    }
    __syncthreads();   // weights are read-only afterwards: no barriers in main loop

    const int wid  = tid >> 6;
    const int lane = tid & 63;
    const int g    = lane >> 4;                  // lane group 0..3
    const int c    = lane & 15;                  // lane col  0..15

    const long long wbase = ((long long)blockIdx.x * 4 + wid) * (32LL * iters);

    #pragma unroll 1
    for (int it = 0; it < iters; ++it) {
        const long long base = wbase + (long long)it * 32;

        // ---- Phase A: build w_v fragments for 2 sample groups ----
        F8 vh[2], vl[2], mx[2];
        #pragma unroll
        for (int grp = 0; grp < 2; ++grp) {
            const long long s = base + grp * 16 + c;
            const float* up = u + s * NSPEC + g * 8;
            float4 ua = *(const float4*)up;
            float4 ub = *(const float4*)(up + 4);
            float xs[8] = {ua.x, ua.y, ua.z, ua.w, ub.x, ub.y, ub.z, ub.w};
            #pragma unroll
            for (int j = 0; j < 8; ++j) {
                float v = __logf(clampf(xs[j], 1e-5f, 60.0f));
                ushort h = f2bh(v);
                vh[grp].u[j] = h;
                vl[grp].u[j] = f2bh(v - bh2f(h));
            }
            // jnp.interp on (near-)uniform grid: direct guess + micro-adjust,
            // comparisons identical to searchsorted-right on the f32 grid.
            float tt = t[s];
            int i0 = (int)(tt * 2047.0f);
            i0 = i0 < 0 ? 0 : (i0 > 2046 ? 2046 : i0);
            while (i0 < 2046 && tt >= tsteps[i0 + 1]) ++i0;
            while (i0 > 0 && tt < tsteps[i0]) --i0;
            float x0 = tsteps[i0], x1 = tsteps[i0 + 1];
            float T = T_tab[i0] + (tt - x0) / (x1 - x0) * (T_tab[i0 + 1] - T_tab[i0]);
            float sp0 = -1.0f / (0.0019872036f * T);
            float sp1 = __logf(T);
            #pragma unroll
            for (int j = 0; j < 8; ++j) mx[grp].u[j] = 0;
            if (g == 0) {   // mix chunk lives in k-slots of lane-group 0 only
                ushort h0 = f2bh(sp0), l0 = f2bh(sp0 - bh2f(h0));
                ushort h1 = f2bh(sp1), l1 = f2bh(sp1 - bh2f(h1));
                mx[grp].u[0] = h0; mx[grp].u[1] = h1;
                mx[grp].u[2] = l0; mx[grp].u[3] = l1;
                mx[grp].u[4] = h0; mx[grp].u[5] = h1;
                mx[grp].u[6] = 0x3F80; mx[grp].u[7] = 0x3F80;  // bf16(1.0) x2 (bias)
            }
        }

        // ---- Phase B: GEMM1 (swapped): acc[grp][m] = I^T[reaction tile m][sample] ----
        f32x4_t acc[2][16];
        #pragma unroll
        for (int grp = 0; grp < 2; ++grp)
            #pragma unroll
            for (int m = 0; m < 16; ++m)
                acc[grp][m] = (f32x4_t){0.f, 0.f, 0.f, 0.f};

        #pragma unroll
        for (int m = 0; m < 16; ++m) {
            const ushort* r1 = &sW1[16 * m + c][0];
            bf16x8_t Wh = __builtin_bit_cast(bf16x8_t, *(const uint4*)(r1 + 16 * g));
            bf16x8_t Wl = __builtin_bit_cast(bf16x8_t, *(const uint4*)(r1 + 16 * g + 8));
            uint4 mz = {0u, 0u, 0u, 0u};
            if (g == 0) mz = *(const uint4*)(r1 + 64);
            bf16x8_t Wm = __builtin_bit_cast(bf16x8_t, mz);
            #pragma unroll
            for (int grp = 0; grp < 2; ++grp) {
                acc[grp][m] = __builtin_amdgcn_mfma_f32_16x16x32_bf16(Wh, vh[grp].v, acc[grp][m], 0, 0, 0);
                acc[grp][m] = __builtin_amdgcn_mfma_f32_16x16x32_bf16(Wh, vl[grp].v, acc[grp][m], 0, 0, 0);
                acc[grp][m] = __builtin_amdgcn_mfma_f32_16x16x32_bf16(Wl, vh[grp].v, acc[grp][m], 0, 0, 0);
                acc[grp][m] = __builtin_amdgcn_mfma_f32_16x16x32_bf16(Wm, mx[grp].v, acc[grp][m], 0, 0, 0);
            }
        }

        // ---- Phase C+D: clamp/exp/split in-register, GEMM2 via 16x16x16 bf16 ----
        f32x4_t accA[2][2], accB[2][2];
        #pragma unroll
        for (int grp = 0; grp < 2; ++grp)
            #pragma unroll
            for (int n = 0; n < 2; ++n) {
                accA[grp][n] = (f32x4_t){0.f, 0.f, 0.f, 0.f};
                accB[grp][n] = (f32x4_t){0.f, 0.f, 0.f, 0.f};
            }

        #pragma unroll
        for (int m = 0; m < 16; ++m) {
            F4 ph[2], pl[2];
            #pragma unroll
            for (int grp = 0; grp < 2; ++grp) {
                f32x4_t a = acc[grp][m];
                #pragma unroll
                for (int j = 0; j < 4; ++j) {
                    float e = __expf(clampf(a[j], -30.0f, 30.0f));
                    ushort h = f2bh(e);
                    ph[grp].u[j] = h;
                    pl[grp].u[j] = f2bh(e - bh2f(h));
                }
            }
            #pragma unroll
            for (int n = 0; n < 2; ++n) {
                const ushort* r2 = &sW2[16 * n + c][m * 32 + 8 * g];
                shortx4_t W2h = __builtin_bit_cast(shortx4_t, *(const uint2*)r2);
                shortx4_t W2l = __builtin_bit_cast(shortx4_t, *(const uint2*)(r2 + 4));
                #pragma unroll
                for (int grp = 0; grp < 2; ++grp) {
                    accA[grp][n] = __builtin_amdgcn_mfma_f32_16x16x16bf16_1k(W2h, ph[grp].v, accA[grp][n], 0, 0, 0);
                    accB[grp][n] = __builtin_amdgcn_mfma_f32_16x16x16bf16_1k(W2h, pl[grp].v, accB[grp][n], 0, 0, 0);
                    accB[grp][n] = __builtin_amdgcn_mfma_f32_16x16x16bf16_1k(W2l, ph[grp].v, accB[grp][n], 0, 0, 0);
                }
            }
        }

        // ---- Phase E: clip + store (float4, consecutive specs per lane) ----
        #pragma unroll
        for (int grp = 0; grp < 2; ++grp) {
            const long long s = base + grp * 16 + c;
            float* op = out + s * NSPEC + 4 * g;
            #pragma unroll
            for (int n = 0; n < 2; ++n) {
                f32x4_t o = accA[grp][n] + accB[grp][n];
                float4 st;
                st.x = clampf(o[0], -1e4f, 1e4f);
                st.y = clampf(o[1], -1e4f, 1e4f);
                st.z = clampf(o[2], -1e4f, 1e4f);
                st.w = clampf(o[3], -1e4f, 1e4f);
                *(float4*)(op + 16 * n) = st;
            }
        }
    }
}

extern "C" void kernel_launch(void* const* d_in, const int* in_sizes, int n_in,
                              void* d_out, int out_size, void* d_ws, size_t ws_size,
                              hipStream_t stream) {
    const float* u      = (const float*)d_in[0];
    const float* t      = (const float*)d_in[1];
    const float* tsteps = (const float*)d_in[2];
    const float* T_tab  = (const float*)d_in[3];
    // d_in[4] = P_tab : computed-but-unused in the reference
    const float* w_in   = (const float*)d_in[5];
    const float* w_b    = (const float*)d_in[6];
    const float* w_out  = (const float*)d_in[7];
    float* out = (float*)d_out;

    const int B = in_sizes[0] / NSPEC;           // 262144
    const int ITERS = 4;
    const int spb = 4 * 32 * ITERS;              // 512 samples per block
    const int grid = B / spb;                    // 512 blocks (2 per CU)
    crnn_mfma<<<grid, 256, 0, stream>>>(u, t, tsteps, T_tab, w_in, w_b, w_out, out, ITERS);
}

// Round 6
// 56.291 us; speedup vs baseline: 3.1708x; 1.8340x over previous
//
#include <hip/hip_runtime.h>

// CRNN fused, round 5: R1 numerics (known-good) + spill-free fused m-loop +
// 512-thread blocks (2/CU, 50% occ) + conflict-free sW2 stride.
// Deliberately NOT using: log2-domain, v_cvt_pk_bf16_f32, fmed3 (R2 regression cluster).
#define NSPEC 32
#define NREAC 256
#define NGRID 2048
#define S2STRIDE 524   // ushorts; 1048B -> b64 read starts uniform mod 32 banks

typedef __bf16 bf16x8_t __attribute__((ext_vector_type(8)));
typedef short shortx4_t __attribute__((ext_vector_type(4)));
typedef float f32x4_t  __attribute__((ext_vector_type(4)));

union F8 { ushort u[8]; uint4 q; bf16x8_t v; };
union F4 { ushort u[4]; uint2 q; shortx4_t v; };

__device__ __forceinline__ ushort f2bh(float x) {          // f32 -> bf16 bits (RNE)
    uint b = __float_as_uint(x);
    return (ushort)((b + 0x7FFFu + ((b >> 16) & 1u)) >> 16);
}
__device__ __forceinline__ float bh2f(ushort h) {           // bf16 bits -> f32 (exact)
    return __uint_as_float(((uint)h) << 16);
}
__device__ __forceinline__ float clampf(float x, float lo, float hi) {
    return fminf(fmaxf(x, lo), hi);
}

__global__ __launch_bounds__(512, 4) void crnn_mfma(
    const float* __restrict__ u,       // [B,32]
    const float* __restrict__ t,       // [B]
    const float* __restrict__ tsteps,  // [2048]
    const float* __restrict__ T_tab,   // [2048]
    const float* __restrict__ w_in,    // [34,256]
    const float* __restrict__ w_b,     // [256]
    const float* __restrict__ w_out,   // [32,256]
    float* __restrict__ out,           // [B,32]
    int iters)
{
    // sW1 row r (reaction): 4 chunks of [8 hi | 8 lo] for k=0..31, then
    // mix(8) = {h32,h33,h32,h33,l32,l33,hb,lb}
    __shared__ ushort sW1[256][72];        // 36 KB, b128 reads conflict-free
    __shared__ ushort sW2[32][S2STRIDE];   // 32.75 KB

    const int tid = threadIdx.x;

    // ---- stage weights: threads [0,256) -> sW1, [256,512) -> sW2 ----
    if (tid < 256) {
        const int r = tid;
        #pragma unroll
        for (int k = 0; k < 32; ++k) {
            float f = w_in[k * NREAC + r];       // coalesced across threads
            ushort h = f2bh(f), l = f2bh(f - bh2f(h));
            sW1[r][(k >> 3) * 16 + (k & 7)]     = h;
            sW1[r][(k >> 3) * 16 + (k & 7) + 8] = l;
        }
        float f32v = w_in[32 * NREAC + r];       // pairs with -1/(R*T)
        float f33v = w_in[33 * NREAC + r];       // pairs with log(T)
        float fbv  = w_b[r];
        ushort h32 = f2bh(f32v), l32 = f2bh(f32v - bh2f(h32));
        ushort h33 = f2bh(f33v), l33 = f2bh(f33v - bh2f(h33));
        ushort hb  = f2bh(fbv),  lb  = f2bh(fbv  - bh2f(hb));
        sW1[r][64] = h32; sW1[r][65] = h33; sW1[r][66] = h32; sW1[r][67] = h33;
        sW1[r][68] = l32; sW1[r][69] = l33; sW1[r][70] = hb;  sW1[r][71] = lb;
    } else {
        const int tt2 = tid - 256;
        const int s2 = tt2 >> 3;                 // spec 0..31
        const int kb = (tt2 & 7) * 32;           // 32 reactions per thread
        for (int k = kb; k < kb + 32; ++k) {
            float f = w_out[s2 * NREAC + k];
            ushort h = f2bh(f), l = f2bh(f - bh2f(h));
            sW2[s2][(k >> 2) * 8 + (k & 3)]     = h;
            sW2[s2][(k >> 2) * 8 + (k & 3) + 4] = l;
        }
    }
    __syncthreads();   // weights read-only afterwards: no barriers in main loop

    const int wid  = tid >> 6;            // 0..7
    const int lane = tid & 63;
    const int g    = lane >> 4;           // 0..3
    const int c    = lane & 15;           // 0..15

    const long long wbase = ((long long)blockIdx.x * 8 + wid) * (32LL * iters);

    #pragma unroll 1
    for (int it = 0; it < iters; ++it) {
        const long long base = wbase + (long long)it * 32;

        // ---- Phase A: build w_v fragments for 2 sample groups (R1-identical) ----
        F8 vh[2], vl[2], mx[2];
        #pragma unroll
        for (int grp = 0; grp < 2; ++grp) {
            const long long s = base + grp * 16 + c;
            const float* up = u + s * NSPEC + g * 8;
            float4 ua = *(const float4*)up;
            float4 ub = *(const float4*)(up + 4);
            float xs[8] = {ua.x, ua.y, ua.z, ua.w, ub.x, ub.y, ub.z, ub.w};
            #pragma unroll
            for (int j = 0; j < 8; ++j) {
                float v = __logf(clampf(xs[j], 1e-5f, 60.0f));
                ushort h = f2bh(v);
                vh[grp].u[j] = h;
                vl[grp].u[j] = f2bh(v - bh2f(h));
            }
            // jnp.interp clone (uniform-grid guess + exact micro-adjust,
            // comparisons identical to searchsorted-right on the f32 grid)
            float tt = t[s];
            int i0 = (int)(tt * 2047.0f);
            i0 = i0 < 0 ? 0 : (i0 > 2046 ? 2046 : i0);
            while (i0 < 2046 && tt >= tsteps[i0 + 1]) ++i0;
            while (i0 > 0 && tt < tsteps[i0]) --i0;
            float x0 = tsteps[i0], x1 = tsteps[i0 + 1];
            float T = T_tab[i0] + (tt - x0) / (x1 - x0) * (T_tab[i0 + 1] - T_tab[i0]);
            float sp0 = -1.0f / (0.0019872036f * T);
            float sp1 = __logf(T);
            #pragma unroll
            for (int j = 0; j < 8; ++j) mx[grp].u[j] = 0;
            if (g == 0) {   // mix chunk lives in k-slots of lane-group 0 only
                ushort h0 = f2bh(sp0), l0 = f2bh(sp0 - bh2f(h0));
                ushort h1 = f2bh(sp1), l1 = f2bh(sp1 - bh2f(h1));
                mx[grp].u[0] = h0; mx[grp].u[1] = h1;
                mx[grp].u[2] = l0; mx[grp].u[3] = l1;
                mx[grp].u[4] = h0; mx[grp].u[5] = h1;
                mx[grp].u[6] = 0x3F80; mx[grp].u[7] = 0x3F80;  // bf16(1.0) bias slots
            }
        }

        // ---- fused GEMM1 -> exp -> GEMM2 per 16-reaction tile m ----
        f32x4_t acc2[2][2];
        #pragma unroll
        for (int grp = 0; grp < 2; ++grp)
            #pragma unroll
            for (int n = 0; n < 2; ++n)
                acc2[grp][n] = (f32x4_t){0.f, 0.f, 0.f, 0.f};

        #pragma unroll 4
        for (int m = 0; m < 16; ++m) {
            const ushort* r1 = &sW1[16 * m + c][0];
            bf16x8_t Wh = __builtin_bit_cast(bf16x8_t, *(const uint4*)(r1 + 16 * g));
            bf16x8_t Wl = __builtin_bit_cast(bf16x8_t, *(const uint4*)(r1 + 16 * g + 8));
            uint4 mzq = make_uint4(0u, 0u, 0u, 0u);
            if (g == 0) mzq = *(const uint4*)(r1 + 64);
            bf16x8_t Wm = __builtin_bit_cast(bf16x8_t, mzq);

            F4 W2h[2], W2l[2];
            #pragma unroll
            for (int n = 0; n < 2; ++n) {
                const ushort* r2 = &sW2[16 * n + c][m * 32 + 8 * g];
                W2h[n].q = *(const uint2*)r2;
                W2l[n].q = *(const uint2*)(r2 + 4);
            }

            #pragma unroll
            for (int grp = 0; grp < 2; ++grp) {
                f32x4_t a = (f32x4_t){0.f, 0.f, 0.f, 0.f};
                a = __builtin_amdgcn_mfma_f32_16x16x32_bf16(Wh, vh[grp].v, a, 0, 0, 0);
                a = __builtin_amdgcn_mfma_f32_16x16x32_bf16(Wh, vl[grp].v, a, 0, 0, 0);
                a = __builtin_amdgcn_mfma_f32_16x16x32_bf16(Wl, vh[grp].v, a, 0, 0, 0);
                a = __builtin_amdgcn_mfma_f32_16x16x32_bf16(Wm, mx[grp].v, a, 0, 0, 0);

                // exp(clip(intermediate)) then hi/lo split (R1-identical math)
                F4 ph, pl;
                #pragma unroll
                for (int j = 0; j < 4; ++j) {
                    float e = __expf(clampf(a[j], -30.0f, 30.0f));
                    ushort h = f2bh(e);
                    ph.u[j] = h;
                    pl.u[j] = f2bh(e - bh2f(h));
                }
                #pragma unroll
                for (int n = 0; n < 2; ++n) {
                    acc2[grp][n] = __builtin_amdgcn_mfma_f32_16x16x16bf16_1k(W2h[n].v, ph.v, acc2[grp][n], 0, 0, 0);
                    acc2[grp][n] = __builtin_amdgcn_mfma_f32_16x16x16bf16_1k(W2h[n].v, pl.v, acc2[grp][n], 0, 0, 0);
                    acc2[grp][n] = __builtin_amdgcn_mfma_f32_16x16x16bf16_1k(W2l[n].v, ph.v, acc2[grp][n], 0, 0, 0);
                }
            }
        }

        // ---- epilogue: clip + store ----
        #pragma unroll
        for (int grp = 0; grp < 2; ++grp) {
            const long long s = base + grp * 16 + c;
            float* op = out + s * NSPEC + 4 * g;
            #pragma unroll
            for (int n = 0; n < 2; ++n) {
                f32x4_t o = acc2[grp][n];
                float4 st;
                st.x = clampf(o[0], -1e4f, 1e4f);
                st.y = clampf(o[1], -1e4f, 1e4f);
                st.z = clampf(o[2], -1e4f, 1e4f);
                st.w = clampf(o[3], -1e4f, 1e4f);
                *(float4*)(op + 16 * n) = st;
            }
        }
    }
}

extern "C" void kernel_launch(void* const* d_in, const int* in_sizes, int n_in,
                              void* d_out, int out_size, void* d_ws, size_t ws_size,
                              hipStream_t stream) {
    const float* u      = (const float*)d_in[0];
    const float* t      = (const float*)d_in[1];
    const float* tsteps = (const float*)d_in[2];
    const float* T_tab  = (const float*)d_in[3];
    // d_in[4] = P_tab : unused in the reference
    const float* w_in   = (const float*)d_in[5];
    const float* w_b    = (const float*)d_in[6];
    const float* w_out  = (const float*)d_in[7];
    float* out = (float*)d_out;

    const int B = in_sizes[0] / NSPEC;           // 262144
    const int ITERS = 2;
    const int spb = 8 * 32 * ITERS;              // 512 samples per block (8 waves)
    const int grid = B / spb;                    // 512 blocks -> 2 per CU
    crnn_mfma<<<grid, 512, 0, stream>>>(u, t, tsteps, T_tab, w_in, w_b, w_out, out, ITERS);
}

// Round 7
// 45.692 us; speedup vs baseline: 3.9063x; 1.2320x over previous
//
#include <hip/hip_runtime.h>

// CRNN fused, round 6: R5 base (verified) + log2-domain + trunc/perm P-split
// + med3 clamps. VALU-cut round; structure, layouts, MFMA sequence unchanged.
#define NSPEC 32
#define NREAC 256
#define NGRID 2048
#define S2STRIDE 524   // ushorts

typedef __bf16 bf16x8_t __attribute__((ext_vector_type(8)));
typedef short shortx4_t __attribute__((ext_vector_type(4)));
typedef float f32x4_t  __attribute__((ext_vector_type(4)));

union F8 { ushort u[8]; uint4 q; bf16x8_t v; };
union F4 { ushort u[4]; uint2 q; shortx4_t v; };

#define LOG2E  1.4426950408889634f
#define CLAMP2 43.280851f           // 30 * log2(e)

__device__ __forceinline__ ushort f2bh(float x) {          // f32 -> bf16 bits (RNE)
    uint b = __float_as_uint(x);
    return (ushort)((b + 0x7FFFu + ((b >> 16) & 1u)) >> 16);
}
__device__ __forceinline__ float bh2f(ushort h) {           // bf16 bits -> f32 (exact)
    return __uint_as_float(((uint)h) << 16);
}
__device__ __forceinline__ float med3(float x, float lo, float hi) {
    return __builtin_amdgcn_fmed3f(x, lo, hi);              // clamp, finite inputs
}
// D = { y.hi16 : x.hi16 }  (low ushort = x's top 16 bits). v_perm_b32:
// sel bytes 0-3 pick from S1 (=x), 4-7 from S0 (=y).
__device__ __forceinline__ uint pack_hi16(float x, float y) {
    return __builtin_amdgcn_perm(__float_as_uint(y), __float_as_uint(x), 0x07060302u);
}
__device__ __forceinline__ float trunc_hi(float x) {        // bf16-trunc as f32
    return __uint_as_float(__float_as_uint(x) & 0xffff0000u);
}

__global__ __launch_bounds__(512, 4) void crnn_mfma(
    const float* __restrict__ u,       // [B,32]
    const float* __restrict__ t,       // [B]
    const float* __restrict__ tsteps,  // [2048]
    const float* __restrict__ T_tab,   // [2048]
    const float* __restrict__ w_in,    // [34,256]
    const float* __restrict__ w_b,     // [256]
    const float* __restrict__ w_out,   // [32,256]
    float* __restrict__ out,           // [B,32]
    int iters)
{
    // sW1 row r: 4 chunks of [8 hi | 8 lo] for k=0..31, then
    // mix(8) = {h32s,h33,h32s,h33,l32s,l33,hb,lb}; w32,w_b pre-scaled by log2e.
    __shared__ ushort sW1[256][72];        // 36 KB
    __shared__ ushort sW2[32][S2STRIDE];   // 32.75 KB

    const int tid = threadIdx.x;

    // ---- stage weights (RNE splits; once per block) ----
    if (tid < 256) {
        const int r = tid;
        #pragma unroll
        for (int k = 0; k < 32; ++k) {
            float f = w_in[k * NREAC + r];           // unscaled: pairs with log2(Y)
            ushort h = f2bh(f), l = f2bh(f - bh2f(h));
            sW1[r][(k >> 3) * 16 + (k & 7)]     = h;
            sW1[r][(k >> 3) * 16 + (k & 7) + 8] = l;
        }
        float f32v = w_in[32 * NREAC + r] * LOG2E;   // pairs with -1/(R*T)
        float f33v = w_in[33 * NREAC + r];           // pairs with log2(T) (no scale)
        float fbv  = w_b[r] * LOG2E;
        ushort h32 = f2bh(f32v), l32 = f2bh(f32v - bh2f(h32));
        ushort h33 = f2bh(f33v), l33 = f2bh(f33v - bh2f(h33));
        ushort hb  = f2bh(fbv),  lb  = f2bh(fbv  - bh2f(hb));
        sW1[r][64] = h32; sW1[r][65] = h33; sW1[r][66] = h32; sW1[r][67] = h33;
        sW1[r][68] = l32; sW1[r][69] = l33; sW1[r][70] = hb;  sW1[r][71] = lb;
    } else {
        const int tt2 = tid - 256;
        const int s2 = tt2 >> 3;
        const int kb = (tt2 & 7) * 32;
        for (int k = kb; k < kb + 32; ++k) {
            float f = w_out[s2 * NREAC + k];
            ushort h = f2bh(f), l = f2bh(f - bh2f(h));
            sW2[s2][(k >> 2) * 8 + (k & 3)]     = h;
            sW2[s2][(k >> 2) * 8 + (k & 3) + 4] = l;
        }
    }
    __syncthreads();   // weights read-only afterwards: no barriers in main loop

    const int wid  = tid >> 6;            // 0..7
    const int lane = tid & 63;
    const int g    = lane >> 4;           // 0..3
    const int c    = lane & 15;           // 0..15

    const long long wbase = ((long long)blockIdx.x * 8 + wid) * (32LL * iters);

    #pragma unroll 1
    for (int it = 0; it < iters; ++it) {
        const long long base = wbase + (long long)it * 32;

        // ---- Phase A: w_v fragments (log2 domain; RNE splits kept here) ----
        F8 vh[2], vl[2], mx[2];
        #pragma unroll
        for (int grp = 0; grp < 2; ++grp) {
            const long long s = base + grp * 16 + c;
            const float* up = u + s * NSPEC + g * 8;
            float4 ua = *(const float4*)up;
            float4 ub = *(const float4*)(up + 4);
            float xs[8] = {ua.x, ua.y, ua.z, ua.w, ub.x, ub.y, ub.z, ub.w};
            #pragma unroll
            for (int j = 0; j < 8; ++j) {
                float v = __builtin_amdgcn_logf(med3(xs[j], 1e-5f, 60.0f)); // log2
                ushort h = f2bh(v);
                vh[grp].u[j] = h;
                vl[grp].u[j] = f2bh(v - bh2f(h));
            }
            // jnp.interp clone (uniform-grid guess + exact micro-adjust)
            float tt = t[s];
            int i0 = (int)(tt * 2047.0f);
            i0 = i0 < 0 ? 0 : (i0 > 2046 ? 2046 : i0);
            while (i0 < 2046 && tt >= tsteps[i0 + 1]) ++i0;
            while (i0 > 0 && tt < tsteps[i0]) --i0;
            float x0 = tsteps[i0], x1 = tsteps[i0 + 1];
            float T = T_tab[i0] + (tt - x0) / (x1 - x0) * (T_tab[i0 + 1] - T_tab[i0]);
            float sp0 = -1.0f / (0.0019872036f * T);     // pairs with w32*log2e
            float sp1 = __builtin_amdgcn_logf(T);        // log2(T), pairs with w33
            #pragma unroll
            for (int j = 0; j < 8; ++j) mx[grp].u[j] = 0;
            if (g == 0) {
                ushort h0 = f2bh(sp0), l0 = f2bh(sp0 - bh2f(h0));
                ushort h1 = f2bh(sp1), l1 = f2bh(sp1 - bh2f(h1));
                mx[grp].u[0] = h0; mx[grp].u[1] = h1;
                mx[grp].u[2] = l0; mx[grp].u[3] = l1;
                mx[grp].u[4] = h0; mx[grp].u[5] = h1;
                mx[grp].u[6] = 0x3F80; mx[grp].u[7] = 0x3F80;  // bf16(1.0) bias
            }
        }

        // ---- fused GEMM1 -> exp2 -> GEMM2 per 16-reaction tile m ----
        f32x4_t acc2[2][2];
        #pragma unroll
        for (int grp = 0; grp < 2; ++grp)
            #pragma unroll
            for (int n = 0; n < 2; ++n)
                acc2[grp][n] = (f32x4_t){0.f, 0.f, 0.f, 0.f};

        #pragma unroll 4
        for (int m = 0; m < 16; ++m) {
            const ushort* r1 = &sW1[16 * m + c][0];
            bf16x8_t Wh = __builtin_bit_cast(bf16x8_t, *(const uint4*)(r1 + 16 * g));
            bf16x8_t Wl = __builtin_bit_cast(bf16x8_t, *(const uint4*)(r1 + 16 * g + 8));
            uint4 mzq = make_uint4(0u, 0u, 0u, 0u);
            if (g == 0) mzq = *(const uint4*)(r1 + 64);
            bf16x8_t Wm = __builtin_bit_cast(bf16x8_t, mzq);

            F4 W2h[2], W2l[2];
            #pragma unroll
            for (int n = 0; n < 2; ++n) {
                const ushort* r2 = &sW2[16 * n + c][m * 32 + 8 * g];
                W2h[n].q = *(const uint2*)r2;
                W2l[n].q = *(const uint2*)(r2 + 4);
            }

            #pragma unroll
            for (int grp = 0; grp < 2; ++grp) {
                f32x4_t a = (f32x4_t){0.f, 0.f, 0.f, 0.f};
                a = __builtin_amdgcn_mfma_f32_16x16x32_bf16(Wh, vh[grp].v, a, 0, 0, 0);
                a = __builtin_amdgcn_mfma_f32_16x16x32_bf16(Wh, vl[grp].v, a, 0, 0, 0);
                a = __builtin_amdgcn_mfma_f32_16x16x32_bf16(Wl, vh[grp].v, a, 0, 0, 0);
                a = __builtin_amdgcn_mfma_f32_16x16x32_bf16(Wm, mx[grp].v, a, 0, 0, 0);

                // exp2(clip) then trunc-split + perm-pack (e > 0 always)
                float e0 = __builtin_amdgcn_exp2f(med3(a[0], -CLAMP2, CLAMP2));
                float e1 = __builtin_amdgcn_exp2f(med3(a[1], -CLAMP2, CLAMP2));
                float e2 = __builtin_amdgcn_exp2f(med3(a[2], -CLAMP2, CLAMP2));
                float e3 = __builtin_amdgcn_exp2f(med3(a[3], -CLAMP2, CLAMP2));
                F4 ph, pl;
                ph.q = make_uint2(pack_hi16(e0, e1), pack_hi16(e2, e3));
                float l0 = e0 - trunc_hi(e0), l1 = e1 - trunc_hi(e1);
                float l2 = e2 - trunc_hi(e2), l3 = e3 - trunc_hi(e3);
                pl.q = make_uint2(pack_hi16(l0, l1), pack_hi16(l2, l3));

                #pragma unroll
                for (int n = 0; n < 2; ++n) {
                    acc2[grp][n] = __builtin_amdgcn_mfma_f32_16x16x16bf16_1k(W2h[n].v, ph.v, acc2[grp][n], 0, 0, 0);
                    acc2[grp][n] = __builtin_amdgcn_mfma_f32_16x16x16bf16_1k(W2h[n].v, pl.v, acc2[grp][n], 0, 0, 0);
                    acc2[grp][n] = __builtin_amdgcn_mfma_f32_16x16x16bf16_1k(W2l[n].v, ph.v, acc2[grp][n], 0, 0, 0);
                }
            }
        }

        // ---- epilogue: clip + store ----
        #pragma unroll
        for (int grp = 0; grp < 2; ++grp) {
            const long long s = base + grp * 16 + c;
            float* op = out + s * NSPEC + 4 * g;
            #pragma unroll
            for (int n = 0; n < 2; ++n) {
                f32x4_t o = acc2[grp][n];
                float4 st;
                st.x = med3(o[0], -1e4f, 1e4f);
                st.y = med3(o[1], -1e4f, 1e4f);
                st.z = med3(o[2], -1e4f, 1e4f);
                st.w = med3(o[3], -1e4f, 1e4f);
                *(float4*)(op + 16 * n) = st;
            }
        }
    }
}

extern "C" void kernel_launch(void* const* d_in, const int* in_sizes, int n_in,
                              void* d_out, int out_size, void* d_ws, size_t ws_size,
                              hipStream_t stream) {
    const float* u      = (const float*)d_in[0];
    const float* t      = (const float*)d_in[1];
    const float* tsteps = (const float*)d_in[2];
    const float* T_tab  = (const float*)d_in[3];
    // d_in[4] = P_tab : unused in the reference
    const float* w_in   = (const float*)d_in[5];
    const float* w_b    = (const float*)d_in[6];
    const float* w_out  = (const float*)d_in[7];
    float* out = (float*)d_out;

    const int B = in_sizes[0] / NSPEC;           // 262144
    const int ITERS = 2;
    const int spb = 8 * 32 * ITERS;              // 512 samples per block (8 waves)
    const int grid = B / spb;                    // 512 blocks -> 2 per CU
    crnn_mfma<<<grid, 512, 0, stream>>>(u, t, tsteps, T_tab, w_in, w_b, w_out, out, ITERS);
}